// Round 6
// baseline (4380.931 us; speedup 1.0000x reference)
//
#include <hip/hip_runtime.h>
#include <math.h>

typedef unsigned long long ull;
typedef unsigned int u32;
typedef unsigned short u16;
typedef _Float16 half2v __attribute__((ext_vector_type(2)));
typedef __bf16 bf16x8 __attribute__((ext_vector_type(8)));
typedef float f32x4 __attribute__((ext_vector_type(4)));

#define H 512
#define STEPS 1024
#define OUTN 11
#define RD 8          // ring depth
#define NROLE 24      // 8 chain0 + 16 chain1

__device__ __forceinline__ float sigm(float x) { return 1.f / (1.f + __expf(-x)); }

// ---- dual-path communication primitives ----
// Fast path (valid when producer+consumer share an XCD): plain store is
// write-through L1->L2; sc0 load bypasses L1 and reads L2. Slow path: relaxed
// agent-scope atomics (memory-side; proven correct in R2-R4). Every value is
// published on BOTH; consumers poll fast 16x then check slow once -> no
// placement assumption can cause a hang or a stale read.
__device__ __forceinline__ ull ld_sc0(const ull* p) {
  ull v;
  asm volatile("global_load_dwordx2 %0, %1, off sc0\n\ts_waitcnt vmcnt(0)"
               : "=v"(v) : "v"(p) : "memory");
  return v;
}
__device__ __forceinline__ ull ld_slow(const ull* p) {
  return __hip_atomic_load((ull*)p, __ATOMIC_RELAXED, __HIP_MEMORY_SCOPE_AGENT);
}
__device__ __forceinline__ void st_dual(ull* fast, ull* slow, ull v) {
  __hip_atomic_store(fast, v, __ATOMIC_RELAXED, __HIP_MEMORY_SCOPE_WORKGROUP); // plain 8B store
  __hip_atomic_store(slow, v, __ATOMIC_RELAXED, __HIP_MEMORY_SCOPE_AGENT);     // memory-side mirror
}
__device__ __forceinline__ ull poll_tag(const ull* fast, const ull* slow, unsigned tag) {
  for (;;) {
#pragma unroll 1
    for (int i = 0; i < 16; ++i) {
      ull p = ld_sc0(fast);
      if ((unsigned)(p >> 32) == tag) return p;
    }
    ull p = ld_slow(slow);
    if ((unsigned)(p >> 32) == tag) return p;
  }
}
__device__ __forceinline__ void poll_ge(const ull* fast, const ull* slow, unsigned need) {
  for (;;) {
#pragma unroll 1
    for (int i = 0; i < 16; ++i) {
      if ((unsigned)ld_sc0(fast) >= need) return;
    }
    if ((unsigned)ld_slow(slow) >= need) return;
  }
}
__device__ __forceinline__ float dot2acc(half2v a, half2v b, float c) {
#if __has_builtin(__builtin_amdgcn_fdot2)
  return __builtin_amdgcn_fdot2(a, b, c, false);
#else
  return c + (float)a.x * (float)b.x + (float)a.y * (float)b.y;
#endif
}
__device__ __forceinline__ u16 f16bits(float x) {
  return __builtin_bit_cast(u16, (_Float16)x);
}
__device__ __forceinline__ half2v bch2(u32 u) { return __builtin_bit_cast(half2v, u); }

// ---------- in-place fp32 -> {bf16 hi, bf16 lo} repack (same 4B/elem) ----------
__device__ __forceinline__ u32 split_bf16(float x) {
  u32 u = __float_as_uint(x);
  u32 rh = (u + 0x7FFFu + ((u >> 16) & 1u)) & 0xFFFF0000u;
  float hf = __uint_as_float(rh);
  float lo = x - hf;
  u32 ul = __float_as_uint(lo);
  u32 rl = (ul + 0x7FFFu + ((ul >> 16) & 1u)) & 0xFFFF0000u;
  return (rh >> 16) | rl;
}

__global__ void cvt_split(float* __restrict__ A, float* __restrict__ B, int nA, int n4) {
  int idx = blockIdx.x * 256 + threadIdx.x;
  if (idx >= n4) return;
  int base = idx * 4;
  float* p = (base < nA) ? (A + base) : (B + (base - nA));
  float4 v = *(float4*)p;
  u32 r0 = split_bf16(v.x), r1 = split_bf16(v.y), r2 = split_bf16(v.z), r3 = split_bf16(v.w);
  uint4 o = make_uint4(r0, r1, r2, r3);
  *(uint4*)p = o;
}

// ---------- MFMA hi/lo bf16 GEMM: xp[M,N] += A[M,K] * B[N,K]^T (split-K atomic) ----------
__global__ __launch_bounds__(256, 2)
void gemm_hilo(const u32* __restrict__ A2, const u32* __restrict__ B2,
               float* __restrict__ C, int M, int N, int K)
{
  __shared__ __align__(16) u16 Ah[64 * 32], Al[64 * 32], Bh[64 * 32], Bl[64 * 32];
  const int z = blockIdx.z;
  const int zstart = z * 151;
  const int nsteps = (z < 3) ? 151 : 150;
  const int mt = blockIdx.x * 64, nt = blockIdx.y * 64;
  const int tid = threadIdx.x;
  const int row = tid >> 2, cg = (tid & 3) * 8;
  const int wave = tid >> 6, lane = tid & 63;
  const int wm = (wave & 1) * 32, wn = (wave >> 1) * 32;
  const int quad = lane >> 4, l16 = lane & 15;

  f32x4 acc[2][2];
#pragma unroll
  for (int i = 0; i < 2; ++i)
#pragma unroll
    for (int j = 0; j < 2; ++j) acc[i][j] = (f32x4)0.f;

  for (int s = 0; s < nsteps; ++s) {
    const int kb = (zstart + s) * 32;
    {
      const u32* ap = A2 + (size_t)(mt + row) * K + kb + cg;
      const u32* bp = B2 + (size_t)(nt + row) * K + kb + cg;
      uint4 a0 = *(const uint4*)ap, a1 = *(const uint4*)(ap + 4);
      uint4 b0 = *(const uint4*)bp, b1 = *(const uint4*)(bp + 4);
      uint4 hi, lo;
      hi = make_uint4((a0.x & 0xFFFF) | (a0.y << 16), (a0.z & 0xFFFF) | (a0.w << 16),
                      (a1.x & 0xFFFF) | (a1.y << 16), (a1.z & 0xFFFF) | (a1.w << 16));
      lo = make_uint4((a0.x >> 16) | (a0.y & 0xFFFF0000u), (a0.z >> 16) | (a0.w & 0xFFFF0000u),
                      (a1.x >> 16) | (a1.y & 0xFFFF0000u), (a1.z >> 16) | (a1.w & 0xFFFF0000u));
      *(uint4*)&Ah[row * 32 + cg] = hi;
      *(uint4*)&Al[row * 32 + cg] = lo;
      hi = make_uint4((b0.x & 0xFFFF) | (b0.y << 16), (b0.z & 0xFFFF) | (b0.w << 16),
                      (b1.x & 0xFFFF) | (b1.y << 16), (b1.z & 0xFFFF) | (b1.w << 16));
      lo = make_uint4((b0.x >> 16) | (b0.y & 0xFFFF0000u), (b0.z >> 16) | (b0.w & 0xFFFF0000u),
                      (b1.x >> 16) | (b1.y & 0xFFFF0000u), (b1.z >> 16) | (b1.w & 0xFFFF0000u));
      *(uint4*)&Bh[row * 32 + cg] = hi;
      *(uint4*)&Bl[row * 32 + cg] = lo;
    }
    __syncthreads();
    bf16x8 ah[2], al[2], bh[2], bl[2];
#pragma unroll
    for (int mf = 0; mf < 2; ++mf) {
      int r = (wm + mf * 16 + l16) * 32 + quad * 8;
      ah[mf] = *reinterpret_cast<const bf16x8*>(&Ah[r]);
      al[mf] = *reinterpret_cast<const bf16x8*>(&Al[r]);
    }
#pragma unroll
    for (int nf = 0; nf < 2; ++nf) {
      int r = (wn + nf * 16 + l16) * 32 + quad * 8;
      bh[nf] = *reinterpret_cast<const bf16x8*>(&Bh[r]);
      bl[nf] = *reinterpret_cast<const bf16x8*>(&Bl[r]);
    }
#pragma unroll
    for (int mf = 0; mf < 2; ++mf)
#pragma unroll
      for (int nf = 0; nf < 2; ++nf) {
        acc[mf][nf] = __builtin_amdgcn_mfma_f32_16x16x32_bf16(ah[mf], bh[nf], acc[mf][nf], 0, 0, 0);
        acc[mf][nf] = __builtin_amdgcn_mfma_f32_16x16x32_bf16(ah[mf], bl[nf], acc[mf][nf], 0, 0, 0);
        acc[mf][nf] = __builtin_amdgcn_mfma_f32_16x16x32_bf16(al[mf], bh[nf], acc[mf][nf], 0, 0, 0);
      }
    __syncthreads();
  }

#pragma unroll
  for (int mf = 0; mf < 2; ++mf)
#pragma unroll
    for (int nf = 0; nf < 2; ++nf)
#pragma unroll
      for (int r = 0; r < 4; ++r) {
        int rw = mt + wm + mf * 16 + quad * 4 + r;
        int cl = nt + wn + nf * 16 + l16;
        atomicAdd(&C[(size_t)rw * N + cl], acc[mf][nf][r]);
      }
}

// ---------------- fp32 GEMM NT (gx0 = xp @ Wih0^T + bih0) ----------------
#define GBM 64
#define GBN 64
#define GBK 64
#define GLD 76

__global__ __launch_bounds__(256, 2)
void gemm_nt(const float* __restrict__ A, const float* __restrict__ B,
             float* __restrict__ C, const float* __restrict__ bias,
             int M, int N, int K)
{
  __shared__ float As[GBM][GLD];
  __shared__ float Bs[GBN][GLD];
  const int mt = blockIdx.x, nt = blockIdx.y;
  const int tid = threadIdx.x;
  const int tx = tid & 15, ty = tid >> 4;

  float acc[4][4] = {{0.f}};

  for (int kb = 0; kb < K; kb += GBK) {
#pragma unroll
    for (int i = 0; i < 4; ++i) {
      int r = ty + i * 16;
      int gk = kb + tx * 4;
      *(float4*)&As[r][tx * 4] = *(const float4*)(A + (size_t)(mt * GBM + r) * K + gk);
      *(float4*)&Bs[r][tx * 4] = *(const float4*)(B + (size_t)(nt * GBN + r) * K + gk);
    }
    __syncthreads();
#pragma unroll
    for (int k4 = 0; k4 < GBK; k4 += 4) {
      float4 a[4], b[4];
#pragma unroll
      for (int i = 0; i < 4; ++i) a[i] = *(const float4*)&As[ty * 4 + i][k4];
#pragma unroll
      for (int j = 0; j < 4; ++j) b[j] = *(const float4*)&Bs[tx * 4 + j][k4];
#pragma unroll
      for (int i = 0; i < 4; ++i)
#pragma unroll
        for (int j = 0; j < 4; ++j) {
          acc[i][j] = fmaf(a[i].x, b[j].x, acc[i][j]);
          acc[i][j] = fmaf(a[i].y, b[j].y, acc[i][j]);
          acc[i][j] = fmaf(a[i].z, b[j].z, acc[i][j]);
          acc[i][j] = fmaf(a[i].w, b[j].w, acc[i][j]);
        }
    }
    __syncthreads();
  }

#pragma unroll
  for (int i = 0; i < 4; ++i) {
    int m = mt * GBM + ty * 4 + i;
#pragma unroll
    for (int j = 0; j < 4; ++j) {
      int n = nt * GBN + tx * 4 + j;
      C[(size_t)m * N + n] = acc[i][j] + bias[n];
    }
  }
}

__global__ void init_xproj(float* __restrict__ xp, const float* __restrict__ b_in) {
  int i = blockIdx.x * 256 + threadIdx.x;
  xp[i] = b_in[i & (H - 1)];
}

__global__ void out_proj(const float* __restrict__ hs1, const float* __restrict__ Wout,
                         const float* __restrict__ bout, float* __restrict__ out) {
  int idx = blockIdx.x * 256 + threadIdx.x;
  if (idx >= STEPS * OUTN) return;
  int t = idx / OUTN, o = idx - t * OUTN;
  const float* h = hs1 + t * H;
  const float* wr = Wout + o * H;
  float acc = 0.f;
#pragma unroll 4
  for (int i = 0; i < H; i += 4) {
    float4 hv = *(const float4*)(h + i);
    float4 wv = *(const float4*)(wr + i);
    acc = fmaf(hv.x, wv.x, acc);
    acc = fmaf(hv.y, wv.y, acc);
    acc = fmaf(hv.z, wv.z, acc);
    acc = fmaf(hv.w, wv.w, acc);
  }
  out[idx] = acc + bout[o];
}

// ---------------- persistent dataflow double-chain LSTM, dual-path comms ----------------
// Role WGs: blockIdx%8==0 (grid 192) -> under round-robin WG->XCD dispatch all 24
// roles share one XCD and the fast (plain-store / sc0-load, L2-local) path engages.
// Placement is a PERF heuristic only: every pair is mirrored via agent-scope
// atomics and every poll falls back to the mirror -> correct on any placement.
__global__ __launch_bounds__(512, 1)
void lstm_chains(const float* __restrict__ gx0,
                 const float* __restrict__ Whh0, const float* __restrict__ bhh0,
                 const float* __restrict__ Wih1, const float* __restrict__ Whh1,
                 const float* __restrict__ bih1, const float* __restrict__ bhh1,
                 float* __restrict__ hs1, float* __restrict__ out,
                 ull* __restrict__ hb0f, ull* __restrict__ hb0s,
                 ull* __restrict__ hb1f, ull* __restrict__ hb1s,
                 ull* __restrict__ flf, ull* __restrict__ fls)
{
  const int tid = threadIdx.x;
  if (blockIdx.x & 7) return;               // non-role WG
  const int wg = blockIdx.x >> 3;           // role 0..23
  const bool role0 = (wg < 8);

  __shared__ __align__(16) u32 hl_u[512];
  __shared__ __align__(16) float gbuf[256];
  __shared__ __align__(16) float gxb[256];

  half2v wgt[8][16];
  float bias[8];
  int rg, ch;

  if (role0) {
    rg = tid >> 4; ch = tid & 15;
    int g = rg >> 3, lub = (rg & 7) * 8;
    int growb = (g << 9) + (wg << 6) + lub;
    const float* wb = Whh0 + (size_t)growb * H + ch * 32;
#pragma unroll
    for (int r = 0; r < 8; ++r) {
      const float* wr = wb + (size_t)r * H;
#pragma unroll
      for (int j4 = 0; j4 < 8; ++j4) {
        float4 f = *(const float4*)(wr + j4 * 4);
        wgt[r][2 * j4]     = half2v{(_Float16)f.x, (_Float16)f.y};
        wgt[r][2 * j4 + 1] = half2v{(_Float16)f.z, (_Float16)f.w};
      }
      bias[r] = bhh0[growb + r];
    }
  } else {
    rg = tid >> 5; ch = tid & 31;
    int g = rg >> 2, lub = (rg & 3) * 8;
    int growb = (g << 9) + ((wg - 8) << 5) + lub;
    const float* wb = (ch < 16) ? (Whh1 + (size_t)growb * H + ch * 32)
                                : (Wih1 + (size_t)growb * H + (ch - 16) * 32);
#pragma unroll
    for (int r = 0; r < 8; ++r) {
      const float* wr = wb + (size_t)r * H;
#pragma unroll
      for (int j4 = 0; j4 < 8; ++j4) {
        float4 f = *(const float4*)(wr + j4 * 4);
        wgt[r][2 * j4]     = half2v{(_Float16)f.x, (_Float16)f.y};
        wgt[r][2 * j4 + 1] = half2v{(_Float16)f.z, (_Float16)f.w};
      }
      bias[r] = bih1[growb + r] + bhh1[growb + r];
    }
  }

  float c_state = 0.f, h_last = 0.f;

  if (role0) {
    const int w = wg;
    for (int t = 0; t < STEPS; ++t) {
      if (tid >= 256) {
        int j = tid - 256;
        gxb[j] = gx0[t * 2048 + ((j >> 6) << 9) + (w << 6) + (j & 63)];
        // ring-reuse throttle off critical path: every 4th tick require
        // chain1 past round t-4 (covers overwrites of slots t..t+3).
        if (j < 16 && (t & 3) == 0 && t > 0)
          poll_ge(&flf[j], &fls[j], (unsigned)(t - 4));
      } else {
        // h0[t-1]: slot (t-1)&7, tag t
        const int off = ((((unsigned)(t + RD - 1)) & (RD - 1)) << 8) + tid;
        ull p = poll_tag(hb0f + off, hb0s + off, (unsigned)t);
        hl_u[tid] = (u32)p;
      }
      __syncthreads();

      float accv[8];
#pragma unroll
      for (int r = 0; r < 8; ++r) accv[r] = 0.f;
      {
        const u32* hp = hl_u + (ch << 4);
        uint4 q0 = *(const uint4*)hp;
        uint4 q1 = *(const uint4*)(hp + 4);
        uint4 q2 = *(const uint4*)(hp + 8);
        uint4 q3 = *(const uint4*)(hp + 12);
        half2v h2[16] = {bch2(q0.x), bch2(q0.y), bch2(q0.z), bch2(q0.w),
                         bch2(q1.x), bch2(q1.y), bch2(q1.z), bch2(q1.w),
                         bch2(q2.x), bch2(q2.y), bch2(q2.z), bch2(q2.w),
                         bch2(q3.x), bch2(q3.y), bch2(q3.z), bch2(q3.w)};
#pragma unroll
        for (int j = 0; j < 16; ++j)
#pragma unroll
          for (int r = 0; r < 8; ++r)
            accv[r] = dot2acc(wgt[r][j], h2[j], accv[r]);
      }
#pragma unroll
      for (int o = 1; o < 16; o <<= 1)
#pragma unroll
        for (int r = 0; r < 8; ++r)
          accv[r] += __shfl_xor(accv[r], o);
      if (ch == 0) {
        float4 ga = *(const float4*)&gxb[rg * 8];
        float4 gb = *(const float4*)&gxb[rg * 8 + 4];
        float4 o0 = make_float4(accv[0] + bias[0] + ga.x, accv[1] + bias[1] + ga.y,
                                accv[2] + bias[2] + ga.z, accv[3] + bias[3] + ga.w);
        float4 o1 = make_float4(accv[4] + bias[4] + gb.x, accv[5] + bias[5] + gb.y,
                                accv[6] + bias[6] + gb.z, accv[7] + bias[7] + gb.w);
        *(float4*)&gbuf[rg * 8] = o0;
        *(float4*)&gbuf[rg * 8 + 4] = o1;
      }
      __syncthreads();

      if (tid < 64) {
        float gi = gbuf[tid], gf = gbuf[64 + tid], gg = gbuf[128 + tid], go = gbuf[192 + tid];
        c_state = sigm(gf) * c_state + sigm(gi) * tanhf(gg);
        float hv = sigm(go) * tanhf(c_state);
        float hnb = __shfl_down(hv, 1);
        if ((tid & 1) == 0) {
          u32 payl = (u32)f16bits(hv) | ((u32)f16bits(hnb) << 16);
          ull pay = ((ull)(unsigned)(t + 1) << 32) | (ull)payl;
          const int off = (((unsigned)t & (RD - 1)) << 8) + (w << 5) + (tid >> 1);
          st_dual(hb0f + off, hb0s + off, pay);
        }
        h_last = hv;
      }
    }
  } else {
    const int v = wg - 8;
    for (int tau = 1; tau <= STEPS; ++tau) {
      const int t = tau - 1;
      if (tid < 256) {
        // h1[t-1]: slot (t-1)&7, tag t
        const int off = ((((unsigned)(t + RD - 1)) & (RD - 1)) << 8) + tid;
        ull p = poll_tag(hb1f + off, hb1s + off, (unsigned)t);
        hl_u[tid] = (u32)p;
      } else {
        // h0[t]: slot t&7, tag t+1
        const int off = (((unsigned)t & (RD - 1)) << 8) + (tid - 256);
        ull p = poll_tag(hb0f + off, hb0s + off, (unsigned)(t + 1));
        hl_u[tid] = (u32)p;
      }
      __syncthreads();

      float accv[8];
#pragma unroll
      for (int r = 0; r < 8; ++r) accv[r] = 0.f;
      {
        const u32* hp = hl_u + (ch << 4);
        uint4 q0 = *(const uint4*)hp;
        uint4 q1 = *(const uint4*)(hp + 4);
        uint4 q2 = *(const uint4*)(hp + 8);
        uint4 q3 = *(const uint4*)(hp + 12);
        half2v h2[16] = {bch2(q0.x), bch2(q0.y), bch2(q0.z), bch2(q0.w),
                         bch2(q1.x), bch2(q1.y), bch2(q1.z), bch2(q1.w),
                         bch2(q2.x), bch2(q2.y), bch2(q2.z), bch2(q2.w),
                         bch2(q3.x), bch2(q3.y), bch2(q3.z), bch2(q3.w)};
#pragma unroll
        for (int j = 0; j < 16; ++j)
#pragma unroll
          for (int r = 0; r < 8; ++r)
            accv[r] = dot2acc(wgt[r][j], h2[j], accv[r]);
      }
#pragma unroll
      for (int o = 1; o < 32; o <<= 1)
#pragma unroll
        for (int r = 0; r < 8; ++r)
          accv[r] += __shfl_xor(accv[r], o);
      if (ch == 0) {
        float4 o0 = make_float4(accv[0] + bias[0], accv[1] + bias[1],
                                accv[2] + bias[2], accv[3] + bias[3]);
        float4 o1 = make_float4(accv[4] + bias[4], accv[5] + bias[5],
                                accv[6] + bias[6], accv[7] + bias[7]);
        *(float4*)&gbuf[rg * 8] = o0;
        *(float4*)&gbuf[rg * 8 + 4] = o1;
      }
      __syncthreads();

      if (tid < 32) {
        int u = (v << 5) + tid;
        float gi = gbuf[tid], gf = gbuf[32 + tid], gg = gbuf[64 + tid], go = gbuf[96 + tid];
        c_state = sigm(gf) * c_state + sigm(gi) * tanhf(gg);
        float hv = sigm(go) * tanhf(c_state);
        float hnb = __shfl_down(hv, 1);
        if ((tid & 1) == 0) {
          u32 payl = (u32)f16bits(hv) | ((u32)f16bits(hnb) << 16);
          ull pay = ((ull)(unsigned)(t + 1) << 32) | (ull)payl;
          const int off = (((unsigned)t & (RD - 1)) << 8) + (v << 4) + (tid >> 1);
          st_dual(hb1f + off, hb1s + off, pay);
        }
        h_last = hv;
        hs1[t * H + u] = hv;               // plain store; flushed at kernel end
      }
      if (tid == 0)
        st_dual(&flf[v], &fls[v], (ull)(unsigned)tau);
    }
  }

  // finals: hn at [11264,12288), cn at [12288,13312)
  if (role0) {
    if (tid < 64) {
      int u = (wg << 6) + tid;
      out[STEPS * OUTN + u] = h_last;
      out[STEPS * OUTN + 2 * H + u] = c_state;
    }
  } else {
    if (tid < 32) {
      int u = ((wg - 8) << 5) + tid;
      out[STEPS * OUTN + H + u] = h_last;
      out[STEPS * OUTN + 3 * H + u] = c_state;
    }
  }
}

// ---------------- host launch ----------------
extern "C" void kernel_launch(void* const* d_in, const int* in_sizes, int n_in,
                              void* d_out, int out_size, void* d_ws, size_t ws_size,
                              hipStream_t stream)
{
  (void)in_sizes; (void)n_in; (void)out_size; (void)ws_size;
  float* inputs = (float*)d_in[0];
  float* W_in   = (float*)d_in[1];
  const float* b_in   = (const float*)d_in[2];
  const float* Wih0   = (const float*)d_in[3];
  const float* Whh0   = (const float*)d_in[4];
  const float* bih0   = (const float*)d_in[5];
  const float* bhh0   = (const float*)d_in[6];
  const float* Wih1   = (const float*)d_in[7];
  const float* Whh1   = (const float*)d_in[8];
  const float* bih1   = (const float*)d_in[9];
  const float* bhh1   = (const float*)d_in[10];
  const float* W_out  = (const float*)d_in[11];
  const float* b_out  = (const float*)d_in[12];
  float* out = (float*)d_out;
  float* ws = (float*)d_ws;

  float* xp  = ws;                        // 1024*512
  float* gx0 = ws + 524288;               // 1024*2048
  float* hs1 = ws + 524288 + 2097152;     // 1024*512
  char* syncb = (char*)(ws + 3145728);    // 12 MB offset
  ull* hb0f = (ull*)syncb;                // 8 slots x 256 pairs x 8B = 16 KB each
  ull* hb0s = (ull*)(syncb + 16384);
  ull* hb1f = (ull*)(syncb + 32768);
  ull* hb1s = (ull*)(syncb + 49152);
  ull* flf  = (ull*)(syncb + 65536);      // 16 x 8B
  ull* fls  = (ull*)(syncb + 65536 + 128);

  hipMemsetAsync(syncb, 0, 65536 + 256, stream);

  {
    const int nA = STEPS * 19296;
    const int n4 = (nA + H * 19296) / 4;
    cvt_split<<<n4 / 256, 256, 0, stream>>>(inputs, W_in, nA, n4);
  }
  init_xproj<<<2048, 256, 0, stream>>>(xp, b_in);
  {
    dim3 g(16, 8, 4);
    gemm_hilo<<<g, 256, 0, stream>>>((const u32*)inputs, (const u32*)W_in, xp,
                                     1024, 512, 19296);
  }
  {
    dim3 g(16, 32, 1);
    gemm_nt<<<g, 256, 0, stream>>>(xp, Wih0, gx0, bih0, 1024, 2048, 512);
  }
  // 192 WGs; the 24 with blockIdx%8==0 take roles (one XCD under round-robin
  // dispatch -> L2 fast path), the rest exit immediately.
  lstm_chains<<<192, 512, 0, stream>>>(gx0, Whh0, bhh0, Wih1, Whh1, bih1, bhh1,
                                       hs1, out, hb0f, hb0s, hb1f, hb1s, flf, fls);
  out_proj<<<44, 256, 0, stream>>>(hs1, W_out, b_out, out);
}

// Round 7
// 3390.289 us; speedup vs baseline: 1.2922x; 1.2922x over previous
//
#include <hip/hip_runtime.h>
#include <math.h>

typedef unsigned long long ull;
typedef unsigned int u32;
typedef unsigned short u16;
typedef _Float16 half2v __attribute__((ext_vector_type(2)));
typedef __bf16 bf16x8 __attribute__((ext_vector_type(8)));
typedef float f32x4 __attribute__((ext_vector_type(4)));

#define H 512
#define STEPS 1024
#define OUTN 11
#define RD 16         // ring depth
#define NC0 24        // h0 consumers (8 chain0 + 16 chain1)
#define NC1 16        // h1 consumers

__device__ __forceinline__ float sigm(float x) { return 1.f / (1.f + __expf(-x)); }

// ---- dual-path comms ----
// Fast path: plain write-through store -> producer XCD L2; consumer re-reads L2
// via buffer_inv (vector-L1 invalidate, CU-local, cheap) + sc0 load. Engages when
// producer/consumer share an XCD (roles at blockIdx%8==0 -> co-XCD under
// round-robin dispatch). Slow path: R4's private per-consumer mailboxes via
// relaxed agent-scope atomics (memory-side; proven). Every value published on
// both; polls try fast 4x then slow 1x -> any placement is correct, never hangs.
__device__ __forceinline__ void l1inv() { asm volatile("buffer_inv" ::: "memory"); }
__device__ __forceinline__ ull ld_sc0(const ull* p) {
  ull v;
  asm volatile("global_load_dwordx2 %0, %1, off sc0\n\ts_waitcnt vmcnt(0)"
               : "=v"(v) : "v"(p) : "memory");
  return v;
}
__device__ __forceinline__ ull ld_slow(const ull* p) {
  return __hip_atomic_load((ull*)p, __ATOMIC_RELAXED, __HIP_MEMORY_SCOPE_AGENT);
}
__device__ __forceinline__ void st_fast(ull* p, ull v) {
  __hip_atomic_store(p, v, __ATOMIC_RELAXED, __HIP_MEMORY_SCOPE_WORKGROUP);
}
__device__ __forceinline__ void st_slow(ull* p, ull v) {
  __hip_atomic_store(p, v, __ATOMIC_RELAXED, __HIP_MEMORY_SCOPE_AGENT);
}
__device__ __forceinline__ ull poll_tag(const ull* fast, const ull* slow, unsigned tag) {
  for (;;) {
#pragma unroll 1
    for (int i = 0; i < 4; ++i) {
      l1inv();
      ull p = ld_sc0(fast);
      if ((unsigned)(p >> 32) == tag) return p;
    }
    ull p = ld_slow(slow);
    if ((unsigned)(p >> 32) == tag) return p;
  }
}
__device__ __forceinline__ void poll_ge(const ull* fast, const ull* slow, unsigned need) {
  for (;;) {
#pragma unroll 1
    for (int i = 0; i < 4; ++i) {
      l1inv();
      if ((unsigned)ld_sc0(fast) >= need) return;
    }
    if ((unsigned)ld_slow(slow) >= need) return;
  }
}
__device__ __forceinline__ float dot2acc(half2v a, half2v b, float c) {
#if __has_builtin(__builtin_amdgcn_fdot2)
  return __builtin_amdgcn_fdot2(a, b, c, false);
#else
  return c + (float)a.x * (float)b.x + (float)a.y * (float)b.y;
#endif
}
__device__ __forceinline__ u16 f16bits(float x) {
  return __builtin_bit_cast(u16, (_Float16)x);
}
__device__ __forceinline__ half2v bch2(u32 u) { return __builtin_bit_cast(half2v, u); }

// ---------- in-place fp32 -> {bf16 hi, bf16 lo} repack (same 4B/elem) ----------
__device__ __forceinline__ u32 split_bf16(float x) {
  u32 u = __float_as_uint(x);
  u32 rh = (u + 0x7FFFu + ((u >> 16) & 1u)) & 0xFFFF0000u;
  float hf = __uint_as_float(rh);
  float lo = x - hf;
  u32 ul = __float_as_uint(lo);
  u32 rl = (ul + 0x7FFFu + ((ul >> 16) & 1u)) & 0xFFFF0000u;
  return (rh >> 16) | rl;
}

__global__ void cvt_split(float* __restrict__ A, float* __restrict__ B, int nA, int n4) {
  int idx = blockIdx.x * 256 + threadIdx.x;
  if (idx >= n4) return;
  int base = idx * 4;
  float* p = (base < nA) ? (A + base) : (B + (base - nA));
  float4 v = *(float4*)p;
  u32 r0 = split_bf16(v.x), r1 = split_bf16(v.y), r2 = split_bf16(v.z), r3 = split_bf16(v.w);
  uint4 o = make_uint4(r0, r1, r2, r3);
  *(uint4*)p = o;
}

// ---------- MFMA hi/lo bf16 GEMM: xp[M,N] += A[M,K] * B[N,K]^T (split-K atomic) ----------
__global__ __launch_bounds__(256, 2)
void gemm_hilo(const u32* __restrict__ A2, const u32* __restrict__ B2,
               float* __restrict__ C, int M, int N, int K)
{
  __shared__ __align__(16) u16 Ah[64 * 32], Al[64 * 32], Bh[64 * 32], Bl[64 * 32];
  const int z = blockIdx.z;
  const int zstart = z * 151;
  const int nsteps = (z < 3) ? 151 : 150;
  const int mt = blockIdx.x * 64, nt = blockIdx.y * 64;
  const int tid = threadIdx.x;
  const int row = tid >> 2, cg = (tid & 3) * 8;
  const int wave = tid >> 6, lane = tid & 63;
  const int wm = (wave & 1) * 32, wn = (wave >> 1) * 32;
  const int quad = lane >> 4, l16 = lane & 15;

  f32x4 acc[2][2];
#pragma unroll
  for (int i = 0; i < 2; ++i)
#pragma unroll
    for (int j = 0; j < 2; ++j) acc[i][j] = (f32x4)0.f;

  for (int s = 0; s < nsteps; ++s) {
    const int kb = (zstart + s) * 32;
    {
      const u32* ap = A2 + (size_t)(mt + row) * K + kb + cg;
      const u32* bp = B2 + (size_t)(nt + row) * K + kb + cg;
      uint4 a0 = *(const uint4*)ap, a1 = *(const uint4*)(ap + 4);
      uint4 b0 = *(const uint4*)bp, b1 = *(const uint4*)(bp + 4);
      uint4 hi, lo;
      hi = make_uint4((a0.x & 0xFFFF) | (a0.y << 16), (a0.z & 0xFFFF) | (a0.w << 16),
                      (a1.x & 0xFFFF) | (a1.y << 16), (a1.z & 0xFFFF) | (a1.w << 16));
      lo = make_uint4((a0.x >> 16) | (a0.y & 0xFFFF0000u), (a0.z >> 16) | (a0.w & 0xFFFF0000u),
                      (a1.x >> 16) | (a1.y & 0xFFFF0000u), (a1.z >> 16) | (a1.w & 0xFFFF0000u));
      *(uint4*)&Ah[row * 32 + cg] = hi;
      *(uint4*)&Al[row * 32 + cg] = lo;
      hi = make_uint4((b0.x & 0xFFFF) | (b0.y << 16), (b0.z & 0xFFFF) | (b0.w << 16),
                      (b1.x & 0xFFFF) | (b1.y << 16), (b1.z & 0xFFFF) | (b1.w << 16));
      lo = make_uint4((b0.x >> 16) | (b0.y & 0xFFFF0000u), (b0.z >> 16) | (b0.w & 0xFFFF0000u),
                      (b1.x >> 16) | (b1.y & 0xFFFF0000u), (b1.z >> 16) | (b1.w & 0xFFFF0000u));
      *(uint4*)&Bh[row * 32 + cg] = hi;
      *(uint4*)&Bl[row * 32 + cg] = lo;
    }
    __syncthreads();
    bf16x8 ah[2], al[2], bh[2], bl[2];
#pragma unroll
    for (int mf = 0; mf < 2; ++mf) {
      int r = (wm + mf * 16 + l16) * 32 + quad * 8;
      ah[mf] = *reinterpret_cast<const bf16x8*>(&Ah[r]);
      al[mf] = *reinterpret_cast<const bf16x8*>(&Al[r]);
    }
#pragma unroll
    for (int nf = 0; nf < 2; ++nf) {
      int r = (wn + nf * 16 + l16) * 32 + quad * 8;
      bh[nf] = *reinterpret_cast<const bf16x8*>(&Bh[r]);
      bl[nf] = *reinterpret_cast<const bf16x8*>(&Bl[r]);
    }
#pragma unroll
    for (int mf = 0; mf < 2; ++mf)
#pragma unroll
      for (int nf = 0; nf < 2; ++nf) {
        acc[mf][nf] = __builtin_amdgcn_mfma_f32_16x16x32_bf16(ah[mf], bh[nf], acc[mf][nf], 0, 0, 0);
        acc[mf][nf] = __builtin_amdgcn_mfma_f32_16x16x32_bf16(ah[mf], bl[nf], acc[mf][nf], 0, 0, 0);
        acc[mf][nf] = __builtin_amdgcn_mfma_f32_16x16x32_bf16(al[mf], bh[nf], acc[mf][nf], 0, 0, 0);
      }
    __syncthreads();
  }

#pragma unroll
  for (int mf = 0; mf < 2; ++mf)
#pragma unroll
    for (int nf = 0; nf < 2; ++nf)
#pragma unroll
      for (int r = 0; r < 4; ++r) {
        int rw = mt + wm + mf * 16 + quad * 4 + r;
        int cl = nt + wn + nf * 16 + l16;
        atomicAdd(&C[(size_t)rw * N + cl], acc[mf][nf][r]);
      }
}

// ---------------- fp32 GEMM NT (gx0 = xp @ Wih0^T + bih0) ----------------
#define GBM 64
#define GBN 64
#define GBK 64
#define GLD 76

__global__ __launch_bounds__(256, 2)
void gemm_nt(const float* __restrict__ A, const float* __restrict__ B,
             float* __restrict__ C, const float* __restrict__ bias,
             int M, int N, int K)
{
  __shared__ float As[GBM][GLD];
  __shared__ float Bs[GBN][GLD];
  const int mt = blockIdx.x, nt = blockIdx.y;
  const int tid = threadIdx.x;
  const int tx = tid & 15, ty = tid >> 4;

  float acc[4][4] = {{0.f}};

  for (int kb = 0; kb < K; kb += GBK) {
#pragma unroll
    for (int i = 0; i < 4; ++i) {
      int r = ty + i * 16;
      int gk = kb + tx * 4;
      *(float4*)&As[r][tx * 4] = *(const float4*)(A + (size_t)(mt * GBM + r) * K + gk);
      *(float4*)&Bs[r][tx * 4] = *(const float4*)(B + (size_t)(nt * GBN + r) * K + gk);
    }
    __syncthreads();
#pragma unroll
    for (int k4 = 0; k4 < GBK; k4 += 4) {
      float4 a[4], b[4];
#pragma unroll
      for (int i = 0; i < 4; ++i) a[i] = *(const float4*)&As[ty * 4 + i][k4];
#pragma unroll
      for (int j = 0; j < 4; ++j) b[j] = *(const float4*)&Bs[tx * 4 + j][k4];
#pragma unroll
      for (int i = 0; i < 4; ++i)
#pragma unroll
        for (int j = 0; j < 4; ++j) {
          acc[i][j] = fmaf(a[i].x, b[j].x, acc[i][j]);
          acc[i][j] = fmaf(a[i].y, b[j].y, acc[i][j]);
          acc[i][j] = fmaf(a[i].z, b[j].z, acc[i][j]);
          acc[i][j] = fmaf(a[i].w, b[j].w, acc[i][j]);
        }
    }
    __syncthreads();
  }

#pragma unroll
  for (int i = 0; i < 4; ++i) {
    int m = mt * GBM + ty * 4 + i;
#pragma unroll
    for (int j = 0; j < 4; ++j) {
      int n = nt * GBN + tx * 4 + j;
      C[(size_t)m * N + n] = acc[i][j] + bias[n];
    }
  }
}

__global__ void init_xproj(float* __restrict__ xp, const float* __restrict__ b_in) {
  int i = blockIdx.x * 256 + threadIdx.x;
  xp[i] = b_in[i & (H - 1)];
}

__global__ void out_proj(const float* __restrict__ hs1, const float* __restrict__ Wout,
                         const float* __restrict__ bout, float* __restrict__ out) {
  int idx = blockIdx.x * 256 + threadIdx.x;
  if (idx >= STEPS * OUTN) return;
  int t = idx / OUTN, o = idx - t * OUTN;
  const float* h = hs1 + t * H;
  const float* wr = Wout + o * H;
  float acc = 0.f;
#pragma unroll 4
  for (int i = 0; i < H; i += 4) {
    float4 hv = *(const float4*)(h + i);
    float4 wv = *(const float4*)(wr + i);
    acc = fmaf(hv.x, wv.x, acc);
    acc = fmaf(hv.y, wv.y, acc);
    acc = fmaf(hv.z, wv.z, acc);
    acc = fmaf(hv.w, wv.w, acc);
  }
  out[idx] = acc + bout[o];
}

// ---------------- persistent dataflow double-chain LSTM ----------------
__global__ __launch_bounds__(512, 1)
void lstm_chains(const float* __restrict__ gx0,
                 const float* __restrict__ Whh0, const float* __restrict__ bhh0,
                 const float* __restrict__ Wih1, const float* __restrict__ Whh1,
                 const float* __restrict__ bih1, const float* __restrict__ bhh1,
                 float* __restrict__ hs1, float* __restrict__ out,
                 ull* __restrict__ hb0f, ull* __restrict__ hb1f,
                 ull* __restrict__ mb0s, ull* __restrict__ mb1s,
                 ull* __restrict__ flf, ull* __restrict__ fls)
{
  const int tid = threadIdx.x;
  if (blockIdx.x & 7) return;               // non-role WG exits immediately
  const int wg = blockIdx.x >> 3;           // role 0..23 (co-XCD under round-robin)
  const bool role0 = (wg < 8);

  __shared__ __align__(16) u32 hl_u[512];
  __shared__ __align__(16) float gbuf[256];
  __shared__ __align__(16) float gxb[256];

  half2v wgt[8][16];
  float bias[8];
  int rg, ch;

  if (role0) {
    rg = tid >> 4; ch = tid & 15;
    int g = rg >> 3, lub = (rg & 7) * 8;
    int growb = (g << 9) + (wg << 6) + lub;
    const float* wb = Whh0 + (size_t)growb * H + ch * 32;
#pragma unroll
    for (int r = 0; r < 8; ++r) {
      const float* wr = wb + (size_t)r * H;
#pragma unroll
      for (int j4 = 0; j4 < 8; ++j4) {
        float4 f = *(const float4*)(wr + j4 * 4);
        wgt[r][2 * j4]     = half2v{(_Float16)f.x, (_Float16)f.y};
        wgt[r][2 * j4 + 1] = half2v{(_Float16)f.z, (_Float16)f.w};
      }
      bias[r] = bhh0[growb + r];
    }
  } else {
    rg = tid >> 5; ch = tid & 31;
    int g = rg >> 2, lub = (rg & 3) * 8;
    int growb = (g << 9) + ((wg - 8) << 5) + lub;
    const float* wb = (ch < 16) ? (Whh1 + (size_t)growb * H + ch * 32)
                                : (Wih1 + (size_t)growb * H + (ch - 16) * 32);
#pragma unroll
    for (int r = 0; r < 8; ++r) {
      const float* wr = wb + (size_t)r * H;
#pragma unroll
      for (int j4 = 0; j4 < 8; ++j4) {
        float4 f = *(const float4*)(wr + j4 * 4);
        wgt[r][2 * j4]     = half2v{(_Float16)f.x, (_Float16)f.y};
        wgt[r][2 * j4 + 1] = half2v{(_Float16)f.z, (_Float16)f.w};
      }
      bias[r] = bih1[growb + r] + bhh1[growb + r];
    }
  }

  float c_state = 0.f, h_last = 0.f;

  if (role0) {
    const int w = wg;
    for (int t = 0; t < STEPS; ++t) {
      if (tid >= 256) {
        int j = tid - 256;
        gxb[j] = gx0[t * 2048 + ((j >> 6) << 9) + (w << 6) + (j & 63)];
        // ring-reuse throttle off critical path: every 8th tick require
        // chain1 past round t-8 (RD=16 -> covers overwrites of slots t..t+7).
        if (j < 16 && (t & 7) == 0 && t > 0)
          poll_ge(&flf[j], &fls[j], (unsigned)(t - 8));
      } else {
        // h0[t-1]: slot (t-1)&15, tag t
        const int slot = (t + RD - 1) & (RD - 1);
        const ull* fast = hb0f + (slot << 8) + tid;
        const ull* slow = mb0s + (((w << 4) + slot) << 8) + tid;   // consumer w
        ull p = poll_tag(fast, slow, (unsigned)t);
        hl_u[tid] = (u32)p;
      }
      __syncthreads();

      float accv[8];
#pragma unroll
      for (int r = 0; r < 8; ++r) accv[r] = 0.f;
      {
        const u32* hp = hl_u + (ch << 4);
        uint4 q0 = *(const uint4*)hp;
        uint4 q1 = *(const uint4*)(hp + 4);
        uint4 q2 = *(const uint4*)(hp + 8);
        uint4 q3 = *(const uint4*)(hp + 12);
        half2v h2[16] = {bch2(q0.x), bch2(q0.y), bch2(q0.z), bch2(q0.w),
                         bch2(q1.x), bch2(q1.y), bch2(q1.z), bch2(q1.w),
                         bch2(q2.x), bch2(q2.y), bch2(q2.z), bch2(q2.w),
                         bch2(q3.x), bch2(q3.y), bch2(q3.z), bch2(q3.w)};
#pragma unroll
        for (int j = 0; j < 16; ++j)
#pragma unroll
          for (int r = 0; r < 8; ++r)
            accv[r] = dot2acc(wgt[r][j], h2[j], accv[r]);
      }
#pragma unroll
      for (int o = 1; o < 16; o <<= 1)
#pragma unroll
        for (int r = 0; r < 8; ++r)
          accv[r] += __shfl_xor(accv[r], o);
      if (ch == 0) {
        float4 ga = *(const float4*)&gxb[rg * 8];
        float4 gb = *(const float4*)&gxb[rg * 8 + 4];
        float4 o0 = make_float4(accv[0] + bias[0] + ga.x, accv[1] + bias[1] + ga.y,
                                accv[2] + bias[2] + ga.z, accv[3] + bias[3] + ga.w);
        float4 o1 = make_float4(accv[4] + bias[4] + gb.x, accv[5] + bias[5] + gb.y,
                                accv[6] + bias[6] + gb.z, accv[7] + bias[7] + gb.w);
        *(float4*)&gbuf[rg * 8] = o0;
        *(float4*)&gbuf[rg * 8 + 4] = o1;
      }
      __syncthreads();

      if (tid < 64) {
        float gi = gbuf[tid], gf = gbuf[64 + tid], gg = gbuf[128 + tid], go = gbuf[192 + tid];
        c_state = sigm(gf) * c_state + sigm(gi) * tanhf(gg);
        float hv = sigm(go) * tanhf(c_state);
        float hnb = __shfl_down(hv, 1);
        if ((tid & 1) == 0) {
          u32 payl = (u32)f16bits(hv) | ((u32)f16bits(hnb) << 16);
          ull pay = ((ull)(unsigned)(t + 1) << 32) | (ull)payl;
          const int slot = t & (RD - 1);
          const int pidx = (w << 5) + (tid >> 1);
          st_fast(hb0f + (slot << 8) + pidx, pay);     // L2 fast ring first
#pragma unroll
          for (int c = 0; c < NC0; ++c)                // private slow mirrors
            st_slow(mb0s + (((c << 4) + slot) << 8) + pidx, pay);
        }
        h_last = hv;
      }
    }
  } else {
    const int v = wg - 8;
    for (int tau = 1; tau <= STEPS; ++tau) {
      const int t = tau - 1;
      if (tid < 256) {
        // h1[t-1]: slot (t-1)&15, tag t; consumer v
        const int slot = (t + RD - 1) & (RD - 1);
        const ull* fast = hb1f + (slot << 8) + tid;
        const ull* slow = mb1s + (((v << 4) + slot) << 8) + tid;
        ull p = poll_tag(fast, slow, (unsigned)t);
        hl_u[tid] = (u32)p;
      } else {
        // h0[t]: slot t&15, tag t+1; consumer 8+v
        const int slot = t & (RD - 1);
        const ull* fast = hb0f + (slot << 8) + (tid - 256);
        const ull* slow = mb0s + ((((8 + v) << 4) + slot) << 8) + (tid - 256);
        ull p = poll_tag(fast, slow, (unsigned)(t + 1));
        hl_u[tid] = (u32)p;
      }
      __syncthreads();

      float accv[8];
#pragma unroll
      for (int r = 0; r < 8; ++r) accv[r] = 0.f;
      {
        const u32* hp = hl_u + (ch << 4);
        uint4 q0 = *(const uint4*)hp;
        uint4 q1 = *(const uint4*)(hp + 4);
        uint4 q2 = *(const uint4*)(hp + 8);
        uint4 q3 = *(const uint4*)(hp + 12);
        half2v h2[16] = {bch2(q0.x), bch2(q0.y), bch2(q0.z), bch2(q0.w),
                         bch2(q1.x), bch2(q1.y), bch2(q1.z), bch2(q1.w),
                         bch2(q2.x), bch2(q2.y), bch2(q2.z), bch2(q2.w),
                         bch2(q3.x), bch2(q3.y), bch2(q3.z), bch2(q3.w)};
#pragma unroll
        for (int j = 0; j < 16; ++j)
#pragma unroll
          for (int r = 0; r < 8; ++r)
            accv[r] = dot2acc(wgt[r][j], h2[j], accv[r]);
      }
#pragma unroll
      for (int o = 1; o < 32; o <<= 1)
#pragma unroll
        for (int r = 0; r < 8; ++r)
          accv[r] += __shfl_xor(accv[r], o);
      if (ch == 0) {
        float4 o0 = make_float4(accv[0] + bias[0], accv[1] + bias[1],
                                accv[2] + bias[2], accv[3] + bias[3]);
        float4 o1 = make_float4(accv[4] + bias[4], accv[5] + bias[5],
                                accv[6] + bias[6], accv[7] + bias[7]);
        *(float4*)&gbuf[rg * 8] = o0;
        *(float4*)&gbuf[rg * 8 + 4] = o1;
      }
      __syncthreads();

      if (tid < 32) {
        int u = (v << 5) + tid;
        float gi = gbuf[tid], gf = gbuf[32 + tid], gg = gbuf[64 + tid], go = gbuf[96 + tid];
        c_state = sigm(gf) * c_state + sigm(gi) * tanhf(gg);
        float hv = sigm(go) * tanhf(c_state);
        float hnb = __shfl_down(hv, 1);
        if ((tid & 1) == 0) {
          u32 payl = (u32)f16bits(hv) | ((u32)f16bits(hnb) << 16);
          ull pay = ((ull)(unsigned)(t + 1) << 32) | (ull)payl;
          const int slot = t & (RD - 1);
          const int pidx = (v << 4) + (tid >> 1);
          st_fast(hb1f + (slot << 8) + pidx, pay);
#pragma unroll
          for (int c = 0; c < NC1; ++c)
            st_slow(mb1s + (((c << 4) + slot) << 8) + pidx, pay);
        }
        h_last = hv;
        hs1[t * H + u] = hv;               // plain store; flushed at kernel end
      }
      if (tid == 0) {
        st_fast(&flf[v], (ull)(unsigned)tau);
        st_slow(&fls[v], (ull)(unsigned)tau);
      }
    }
  }

  // finals: hn at [11264,12288), cn at [12288,13312)
  if (role0) {
    if (tid < 64) {
      int u = (wg << 6) + tid;
      out[STEPS * OUTN + u] = h_last;
      out[STEPS * OUTN + 2 * H + u] = c_state;
    }
  } else {
    if (tid < 32) {
      int u = ((wg - 8) << 5) + tid;
      out[STEPS * OUTN + H + u] = h_last;
      out[STEPS * OUTN + 3 * H + u] = c_state;
    }
  }
}

// ---------------- host launch ----------------
extern "C" void kernel_launch(void* const* d_in, const int* in_sizes, int n_in,
                              void* d_out, int out_size, void* d_ws, size_t ws_size,
                              hipStream_t stream)
{
  (void)in_sizes; (void)n_in; (void)out_size; (void)ws_size;
  float* inputs = (float*)d_in[0];
  float* W_in   = (float*)d_in[1];
  const float* b_in   = (const float*)d_in[2];
  const float* Wih0   = (const float*)d_in[3];
  const float* Whh0   = (const float*)d_in[4];
  const float* bih0   = (const float*)d_in[5];
  const float* bhh0   = (const float*)d_in[6];
  const float* Wih1   = (const float*)d_in[7];
  const float* Whh1   = (const float*)d_in[8];
  const float* bih1   = (const float*)d_in[9];
  const float* bhh1   = (const float*)d_in[10];
  const float* W_out  = (const float*)d_in[11];
  const float* b_out  = (const float*)d_in[12];
  float* out = (float*)d_out;
  float* ws = (float*)d_ws;

  float* xp  = ws;                        // 1024*512
  float* gx0 = ws + 524288;               // 1024*2048
  float* hs1 = ws + 524288 + 2097152;     // 1024*512
  char* syncb = (char*)(ws + 3145728);    // 12 MB offset
  // layout: fast rings (RD*256*8B each), private slow mirrors, flags
  ull* hb0f = (ull*)syncb;                              // 32 KB
  ull* hb1f = (ull*)(syncb + 32768);                    // 32 KB
  ull* mb0s = (ull*)(syncb + 65536);                    // 24*16*256*8 = 768 KB
  ull* mb1s = (ull*)(syncb + 65536 + 786432);           // 16*16*256*8 = 512 KB
  ull* flf  = (ull*)(syncb + 1376256);                  // 16*8 B
  ull* fls  = (ull*)(syncb + 1376384);                  // 16*8 B

  hipMemsetAsync(syncb, 0, 1376512, stream);

  {
    const int nA = STEPS * 19296;
    const int n4 = (nA + H * 19296) / 4;
    cvt_split<<<n4 / 256, 256, 0, stream>>>(inputs, W_in, nA, n4);
  }
  init_xproj<<<2048, 256, 0, stream>>>(xp, b_in);
  {
    dim3 g(16, 8, 4);
    gemm_hilo<<<g, 256, 0, stream>>>((const u32*)inputs, (const u32*)W_in, xp,
                                     1024, 512, 19296);
  }
  {
    dim3 g(16, 32, 1);
    gemm_nt<<<g, 256, 0, stream>>>(xp, Wih0, gx0, bih0, 1024, 2048, 512);
  }
  // 192 WGs; the 24 with blockIdx%8==0 take roles (co-XCD under round-robin
  // dispatch -> L2 fast path), the rest exit immediately.
  lstm_chains<<<192, 512, 0, stream>>>(gx0, Whh0, bhh0, Wih1, Whh1, bih1, bhh1,
                                       hs1, out, hb0f, hb1f, mb0s, mb1s, flf, fls);
  out_proj<<<44, 256, 0, stream>>>(hs1, W_out, b_out, out);
}